// Round 2
// 284.188 us; speedup vs baseline: 1.0462x; 1.0462x over previous
//
#include <hip/hip_runtime.h>

// Problem constants
constexpr int kE = 65536, kNTOT = 8192;

// ---------------- threefry2x32 (JAX-exact, 20 rounds) ----------------
__host__ __device__ __forceinline__ void tf_round(unsigned& x0, unsigned& x1, int r) {
  x0 += x1;
  x1 = (x1 << r) | (x1 >> (32 - r));
  x1 ^= x0;
}
__host__ __device__ __forceinline__ void tf2x32(unsigned k0, unsigned k1,
                                                unsigned& x0, unsigned& x1) {
  unsigned ks2 = k0 ^ k1 ^ 0x1BD11BDAu;
  x0 += k0; x1 += k1;
  tf_round(x0,x1,13); tf_round(x0,x1,15); tf_round(x0,x1,26); tf_round(x0,x1,6);
  x0 += k1; x1 += ks2 + 1u;
  tf_round(x0,x1,17); tf_round(x0,x1,29); tf_round(x0,x1,16); tf_round(x0,x1,24);
  x0 += ks2; x1 += k0 + 2u;
  tf_round(x0,x1,13); tf_round(x0,x1,15); tf_round(x0,x1,26); tf_round(x0,x1,6);
  x0 += k0; x1 += k1 + 3u;
  tf_round(x0,x1,17); tf_round(x0,x1,29); tf_round(x0,x1,16); tf_round(x0,x1,24);
  x0 += k1; x1 += ks2 + 4u;
  tf_round(x0,x1,13); tf_round(x0,x1,15); tf_round(x0,x1,26); tf_round(x0,x1,6);
  x0 += ks2; x1 += k0 + 5u;
}

// bits -> N(0,1), replicating jax.random.normal f32 path (partitionable threefry)
__device__ __forceinline__ float bits_to_normal(unsigned bits) {
  float f = __uint_as_float((bits >> 9) | 0x3f800000u) - 1.0f;  // [0,1)
  const float LO = -0.99999994f;
  float u = fmaf(f, 2.0f, LO);
  u = fmaxf(u, LO);
  float w = -log1pf(-u * u);
  float p;
  if (w < 5.0f) {
    w -= 2.5f;
    p = 2.81022636e-08f;
    p = fmaf(p, w, 3.43273939e-07f);
    p = fmaf(p, w, -3.5233877e-06f);
    p = fmaf(p, w, -4.39150654e-06f);
    p = fmaf(p, w, 0.00021858087f);
    p = fmaf(p, w, -0.00125372503f);
    p = fmaf(p, w, -0.00417768164f);
    p = fmaf(p, w, 0.246640727f);
    p = fmaf(p, w, 1.50140941f);
  } else {
    w = sqrtf(w) - 3.0f;
    p = -0.000200214257f;
    p = fmaf(p, w, 0.000100950558f);
    p = fmaf(p, w, 0.00134934322f);
    p = fmaf(p, w, -0.00367342844f);
    p = fmaf(p, w, 0.00573950773f);
    p = fmaf(p, w, -0.0076224613f);
    p = fmaf(p, w, 0.00943887047f);
    p = fmaf(p, w, 1.00167406f);
    p = fmaf(p, w, 2.83297682f);
  }
  return 1.41421356f * (p * u);
}

__device__ __forceinline__ float redmax32(float v) {
#pragma unroll
  for (int o = 16; o > 0; o >>= 1) v = fmaxf(v, __shfl_xor(v, o));
  return v;
}
__device__ __forceinline__ float redsum32(float v) {
#pragma unroll
  for (int o = 16; o > 0; o >>= 1) v += __shfl_xor(v, o);
  return v;
}

// ================= CSR build (multi-block) + agg/rfp zeroing =================
__global__ __launch_bounds__(256) void hist_kern(const int* __restrict__ eiR,
                                                 const int* __restrict__ eiP,
                                                 int* __restrict__ offR,
                                                 int* __restrict__ offP,
                                                 float* __restrict__ aggz,
                                                 float* __restrict__ rfpz) {
  int i = blockIdx.x * 256 + threadIdx.x;  // 0..131071
  float4 z4 = make_float4(0.f, 0.f, 0.f, 0.f);
  float4* z = reinterpret_cast<float4*>(aggz) + i * 2;
  z[0] = z4; z[1] = z4;
  reinterpret_cast<float2*>(rfpz)[i] = make_float2(0.f, 0.f);  // rfp0 accum target
  const int* ei = (i < kE) ? eiR : eiP;
  int* off = (i < kE) ? offR : offP;
  int e = i & (kE - 1);
  atomicAdd(&off[ei[kE + e]], 1);
}

// 2 blocks (one per graph): in-place exclusive scan of off[] (counts -> offsets)
__global__ __launch_bounds__(256) void scan_kern(int* __restrict__ offR,
                                                 int* __restrict__ offP) {
  int* off = blockIdx.x ? offP : offR;
  int t = threadIdx.x;
  int base = t * 32;
  int v[32];
#pragma unroll
  for (int i = 0; i < 32; ++i) v[i] = off[base + i];
  int sum = 0;
#pragma unroll
  for (int i = 0; i < 32; ++i) sum += v[i];
  int lane = t & 63, w = t >> 6;
  int incl = sum;
#pragma unroll
  for (int o = 1; o < 64; o <<= 1) {
    int y = __shfl_up(incl, o);
    if (lane >= o) incl += y;
  }
  __shared__ int wsum[4];
  if (lane == 63) wsum[w] = incl;
  __syncthreads();
  int woff = 0;
#pragma unroll
  for (int i = 0; i < 4; ++i) if (i < w) woff += wsum[i];
  int running = woff + incl - sum;
#pragma unroll
  for (int i = 0; i < 32; ++i) {
    off[base + i] = running;
    running += v[i];
  }
}

__global__ __launch_bounds__(256) void scatter_kern(
    const int* __restrict__ eiR, const int* __restrict__ eiP,
    int* __restrict__ offR, int* __restrict__ offP,
    int* __restrict__ permR, int* __restrict__ permP,
    int* __restrict__ srcsR, int* __restrict__ srcsP,
    int* __restrict__ dstsR, int* __restrict__ dstsP) {
  int i = blockIdx.x * 256 + threadIdx.x;
  const int* ei = (i < kE) ? eiR : eiP;
  int* off = (i < kE) ? offR : offP;
  int* perm = (i < kE) ? permR : permP;
  int* srcs = (i < kE) ? srcsR : srcsP;
  int* dsts = (i < kE) ? dstsR : dstsP;
  int e = i & (kE - 1);
  int dst = ei[kE + e];
  int pos = atomicAdd(&off[dst], 1);
  perm[pos] = e;
  srcs[pos] = ei[e];
  dsts[pos] = dst;
}

// ====== xw_gemm: per-NODE xw = in @ W  (in: [8192,KK], W: [KK,64]) ======
// Algebraic factor: relu(x[src]@Wm + ef@We) == relu((x@Wm)[src] + ef@We),
// so the Wm matmul is done once per node (8192 rows) instead of per edge (65536).
template <int KK>
__global__ __launch_bounds__(256) void xw_gemm(
    const float* __restrict__ inR, const float* __restrict__ inP,
    float* __restrict__ xwR, float* __restrict__ xwP,
    const float* __restrict__ W) {
  __shared__ float sX[KK][68];
  __shared__ float sW[KK][68];
  bool isP = blockIdx.x >= 128;
  const float* in = isP ? inP : inR;
  float* xw = isP ? xwP : xwR;
  int n0 = (blockIdx.x & 127) * 64;
  int t = threadIdx.x;
#pragma unroll
  for (int idx = 0; idx < KK * 64 / 1024; ++idx) {
    int q = t * 4 + idx * 1024;
    int k = q >> 6, j = q & 63;  // W is [KK][64] row-major
    *reinterpret_cast<float4*>(&sW[k][j]) = *reinterpret_cast<const float4*>(W + q);
    int r = q / KK, kk = q & (KK - 1);  // in tile is [64][KK] row-major
    float4 v = *reinterpret_cast<const float4*>(in + (size_t)n0 * KK + q);
    sX[kk][r] = v.x; sX[kk + 1][r] = v.y; sX[kk + 2][r] = v.z; sX[kk + 3][r] = v.w;
  }
  __syncthreads();
  int tn = (t & 15) * 4, tj = (t >> 4) * 4;
  float acc[4][4] = {};
#pragma unroll 8
  for (int k = 0; k < KK; ++k) {
    float4 a = *reinterpret_cast<const float4*>(&sX[k][tn]);
    float4 b = *reinterpret_cast<const float4*>(&sW[k][tj]);
    acc[0][0] = fmaf(a.x, b.x, acc[0][0]); acc[0][1] = fmaf(a.x, b.y, acc[0][1]);
    acc[0][2] = fmaf(a.x, b.z, acc[0][2]); acc[0][3] = fmaf(a.x, b.w, acc[0][3]);
    acc[1][0] = fmaf(a.y, b.x, acc[1][0]); acc[1][1] = fmaf(a.y, b.y, acc[1][1]);
    acc[1][2] = fmaf(a.y, b.z, acc[1][2]); acc[1][3] = fmaf(a.y, b.w, acc[1][3]);
    acc[2][0] = fmaf(a.z, b.x, acc[2][0]); acc[2][1] = fmaf(a.z, b.y, acc[2][1]);
    acc[2][2] = fmaf(a.z, b.z, acc[2][2]); acc[2][3] = fmaf(a.z, b.w, acc[2][3]);
    acc[3][0] = fmaf(a.w, b.x, acc[3][0]); acc[3][1] = fmaf(a.w, b.y, acc[3][1]);
    acc[3][2] = fmaf(a.w, b.z, acc[3][2]); acc[3][3] = fmaf(a.w, b.w, acc[3][3]);
  }
#pragma unroll
  for (int i = 0; i < 4; ++i) {
    *reinterpret_cast<float4*>(&xw[(size_t)(n0 + tn + i) * 64 + tj]) =
        make_float4(acc[i][0], acc[i][1], acc[i][2], acc[i][3]);
  }
}

// ====== msg_edge: msg = relu(xw[src] + ef@We); fused segment-reduce ======
__global__ __launch_bounds__(256) void msg_edge(
    const float* __restrict__ xwR, const float* __restrict__ efR,
    const int* __restrict__ srcsR, const int* __restrict__ permR,
    const int* __restrict__ dstsR, float* __restrict__ aggR,
    const float* __restrict__ xwP, const float* __restrict__ efP,
    const int* __restrict__ srcsP, const int* __restrict__ permP,
    const int* __restrict__ dstsP, float* __restrict__ aggP,
    const float* __restrict__ We) {
  __shared__ float sEF[16][68];
  __shared__ float sW[16][68];
  __shared__ float sOut[64][68];
  __shared__ int sDst[64];
  __shared__ int sSrc[64];
  __shared__ int sPerm[64];
  bool isP = blockIdx.x >= 1024;
  const float* xw = isP ? xwP : xwR;
  const float* ef = isP ? efP : efR;
  const int* srcs = isP ? srcsP : srcsR;
  const int* perm = isP ? permP : permR;
  const int* dsts = isP ? dstsP : dstsR;
  float* agg = isP ? aggP : aggR;
  int i0 = (blockIdx.x & 1023) * 64;
  int t = threadIdx.x;
  {
    int q = t * 4;
    int k = q >> 6, j = q & 63;
    *reinterpret_cast<float4*>(&sW[k][j]) = *reinterpret_cast<const float4*>(We + q);
  }
  if (t < 64) {
    sDst[t] = dsts[i0 + t];
    sSrc[t] = srcs[i0 + t];
    sPerm[t] = perm[i0 + t];
  }
  __syncthreads();
  // gather+transpose ef rows (single 16-k slab): 4 lanes <-> 4 edges at one k-quad
  {
    int l = t & 3;
    int g = t >> 2;            // 0..63
    int rb = g >> 2;           // r-block of 4 (0..15)
    int kq = g & 3;            // k-quad (0..3)
    int gbase = (t & 63) & ~3;
    int k4 = kq * 4;
    int r = rb * 4 + l;
    const float* rptr = ef + (size_t)sPerm[r] * 16 + k4;
    float4 v = *reinterpret_cast<const float4*>(rptr);
    float vc[4] = {v.x, v.y, v.z, v.w};
    float out[4];
#pragma unroll
    for (int c = 0; c < 4; ++c) {
      float val = vc[(l - c) & 3];
      out[(l + c) & 3] = __shfl(val, gbase + ((l + c) & 3), 64);
    }
    *reinterpret_cast<float4*>(&sEF[k4 + l][rb * 4]) =
        make_float4(out[0], out[1], out[2], out[3]);
  }
  __syncthreads();
  int tn = (t & 15) * 4, tj = (t >> 4) * 4;
  float acc[4][4] = {};
#pragma unroll
  for (int k = 0; k < 16; ++k) {
    float4 a = *reinterpret_cast<const float4*>(&sEF[k][tn]);
    float4 b = *reinterpret_cast<const float4*>(&sW[k][tj]);
    acc[0][0] = fmaf(a.x, b.x, acc[0][0]); acc[0][1] = fmaf(a.x, b.y, acc[0][1]);
    acc[0][2] = fmaf(a.x, b.z, acc[0][2]); acc[0][3] = fmaf(a.x, b.w, acc[0][3]);
    acc[1][0] = fmaf(a.y, b.x, acc[1][0]); acc[1][1] = fmaf(a.y, b.y, acc[1][1]);
    acc[1][2] = fmaf(a.y, b.z, acc[1][2]); acc[1][3] = fmaf(a.y, b.w, acc[1][3]);
    acc[2][0] = fmaf(a.z, b.x, acc[2][0]); acc[2][1] = fmaf(a.z, b.y, acc[2][1]);
    acc[2][2] = fmaf(a.z, b.z, acc[2][2]); acc[2][3] = fmaf(a.z, b.w, acc[2][3]);
    acc[3][0] = fmaf(a.w, b.x, acc[3][0]); acc[3][1] = fmaf(a.w, b.y, acc[3][1]);
    acc[3][2] = fmaf(a.w, b.z, acc[3][2]); acc[3][3] = fmaf(a.w, b.w, acc[3][3]);
  }
  // add gathered per-node xw[src] rows, relu, stage output tile
#pragma unroll
  for (int i = 0; i < 4; ++i) {
    float4 g = *reinterpret_cast<const float4*>(xw + (size_t)sSrc[tn + i] * 64 + tj);
    *reinterpret_cast<float4*>(&sOut[tn + i][tj]) =
        make_float4(fmaxf(acc[i][0] + g.x, 0.f), fmaxf(acc[i][1] + g.y, 0.f),
                    fmaxf(acc[i][2] + g.z, 0.f), fmaxf(acc[i][3] + g.w, 0.f));
  }
  __syncthreads();
  // segment-reduce: 64 cols x 4 row-chunks of 16; one atomic per dst-run per col
  int col = t & 63;
  int r0l = (t >> 6) * 16;
  float run = 0.f;
  int rd = sDst[r0l];
#pragma unroll
  for (int r = 0; r < 16; ++r) {
    int d = sDst[r0l + r];
    if (d != rd) {
      unsafeAtomicAdd(&agg[(size_t)rd * 64 + col], run);
      run = 0.f; rd = d;
    }
    run += sOut[r0l + r][col];
  }
  unsafeAtomicAdd(&agg[(size_t)rd * 64 + col], run);
}

// ====== node1 dense tiled GEMM: h = relu(X@Ws + agg + b); re-zeroes agg ======
__global__ __launch_bounds__(256) void node1_gemm(
    const float* __restrict__ xR, float* __restrict__ aggR, float* __restrict__ hR,
    const float* __restrict__ xP, float* __restrict__ aggP, float* __restrict__ hP,
    const float* __restrict__ Ws, const float* __restrict__ bias) {
  __shared__ float sX[64][68];
  __shared__ float sW[64][68];
  bool isP = blockIdx.x >= 128;
  const float* x = isP ? xP : xR;
  float* agg = isP ? aggP : aggR;
  float* h = isP ? hP : hR;
  int n0 = (blockIdx.x & 127) * 64;
  int t = threadIdx.x;
#pragma unroll
  for (int idx = 0; idx < 4; ++idx) {
    int q = t * 4 + idx * 1024;
    int k = q >> 6, j = q & 63;
    *reinterpret_cast<float4*>(&sW[k][j]) = *reinterpret_cast<const float4*>(Ws + q);
    float4 v = *reinterpret_cast<const float4*>(x + (size_t)n0 * 64 + q);
    sX[j + 0][k] = v.x; sX[j + 1][k] = v.y; sX[j + 2][k] = v.z; sX[j + 3][k] = v.w;
  }
  __syncthreads();
  int tn = (t & 15) * 4, tj = (t >> 4) * 4;
  float acc[4][4] = {};
#pragma unroll 8
  for (int k = 0; k < 64; ++k) {
    float4 a = *reinterpret_cast<const float4*>(&sX[k][tn]);
    float4 b = *reinterpret_cast<const float4*>(&sW[k][tj]);
    acc[0][0] = fmaf(a.x, b.x, acc[0][0]); acc[0][1] = fmaf(a.x, b.y, acc[0][1]);
    acc[0][2] = fmaf(a.x, b.z, acc[0][2]); acc[0][3] = fmaf(a.x, b.w, acc[0][3]);
    acc[1][0] = fmaf(a.y, b.x, acc[1][0]); acc[1][1] = fmaf(a.y, b.y, acc[1][1]);
    acc[1][2] = fmaf(a.y, b.z, acc[1][2]); acc[1][3] = fmaf(a.y, b.w, acc[1][3]);
    acc[2][0] = fmaf(a.z, b.x, acc[2][0]); acc[2][1] = fmaf(a.z, b.y, acc[2][1]);
    acc[2][2] = fmaf(a.z, b.z, acc[2][2]); acc[2][3] = fmaf(a.z, b.w, acc[2][3]);
    acc[3][0] = fmaf(a.w, b.x, acc[3][0]); acc[3][1] = fmaf(a.w, b.y, acc[3][1]);
    acc[3][2] = fmaf(a.w, b.z, acc[3][2]); acc[3][3] = fmaf(a.w, b.w, acc[3][3]);
  }
  float4 bv = *reinterpret_cast<const float4*>(bias + tj);
  float4 z4 = make_float4(0.f, 0.f, 0.f, 0.f);
#pragma unroll
  for (int i = 0; i < 4; ++i) {
    int n = n0 + tn + i;
    float4 g = *reinterpret_cast<const float4*>(&agg[(size_t)n * 64 + tj]);
    *reinterpret_cast<float4*>(&agg[(size_t)n * 64 + tj]) = z4;  // re-arm for next iter
    float4 o;
    o.x = fmaxf(acc[i][0] + g.x + bv.x, 0.f);
    o.y = fmaxf(acc[i][1] + g.y + bv.y, 0.f);
    o.z = fmaxf(acc[i][2] + g.z + bv.z, 0.f);
    o.w = fmaxf(acc[i][3] + g.w + bv.w, 0.f);
    *reinterpret_cast<float4*>(&h[(size_t)n * 64 + tj]) = o;
  }
}

// ====== fused rfp partial:  rfp[b,p,i] += sum_r sm[r][p] * rfb[r][i] ======
__device__ __forceinline__ void rfp_partial(const float sm[16][128],
                                            const float rfb[16][32],
                                            float* __restrict__ rfpB, int t) {
  float rfc[16];
  int iw = t & 31;
#pragma unroll
  for (int r = 0; r < 16; ++r) rfc[r] = rfb[r][iw];
#pragma unroll
  for (int rep = 0; rep < 16; ++rep) {
    int p = rep * 8 + (t >> 5);
    float a = 0.f;
#pragma unroll
    for (int r = 0; r < 16; ++r) a = fmaf(sm[r][p], rfc[r], a);  // sm read = broadcast
    unsafeAtomicAdd(&rfpB[p * 32 + iw], a);  // lanes 0..31 -> 128B coalesced
  }
}

// block-local RNG: generate exactly this block's 16x32 rfr tile (JAX index = a1)
__device__ __forceinline__ void gen_rfr_tile(float* __restrict__ rfr,
                                             float rfb[16][32], int b, int r0,
                                             int t, unsigned fk0, unsigned fk1) {
  unsigned base = (unsigned)((b * 128 + r0) * 32);
#pragma unroll
  for (int q = 0; q < 2; ++q) {
    unsigned j = (unsigned)(q * 256 + t);
    unsigned i = base + j;
    unsigned a0 = 0u, a1 = i;
    tf2x32(fk0, fk1, a0, a1);
    float v = bits_to_normal(a0 ^ a1);
    rfr[i] = v;
    rfb[j >> 5][j & 31] = v;
  }
}

// ====== mhat_soft: Mhat tile + fused row softmax (-> out M0, in-reg) +
//        it0 RNG (block-local) + rfp0 partial. Msoft never materialized. ======
__global__ __launch_bounds__(256) void mhat_soft(
    const float* __restrict__ hR, const float* __restrict__ hP,
    float* __restrict__ Mhat, float* __restrict__ M0out,
    float* __restrict__ rfr, float* __restrict__ rfp,
    unsigned fk0, unsigned fk1) {
  __shared__ float hr[16][66];
  __shared__ float hp[128][66];
  __shared__ float sm[16][128];
  __shared__ float rfb[16][32];
  int gid = blockIdx.x, t = threadIdx.x;
  int b = gid >> 3, r0 = (gid & 7) * 16;
  gen_rfr_tile(rfr, rfb, b, r0, t, fk0, fk1);
  const float* hrG = hR + ((size_t)(b * 128 + r0)) * 64;
  {
    int q = t * 4; int r = q >> 6, d = q & 63;
    float4 v = *reinterpret_cast<const float4*>(hrG + q);
    hr[r][d] = v.x; hr[r][d + 1] = v.y; hr[r][d + 2] = v.z; hr[r][d + 3] = v.w;
  }
  const float* hpG = hP + (size_t)b * 128 * 64;
#pragma unroll
  for (int rep = 0; rep < 8; ++rep) {
    int q = (rep * 256 + t) * 4; int p = q >> 6, d = q & 63;
    float4 v = *reinterpret_cast<const float4*>(hpG + q);
    hp[p][d] = v.x; hp[p][d + 1] = v.y; hp[p][d + 2] = v.z; hp[p][d + 3] = v.w;
  }
  __syncthreads();
  int tx = t & 31, ty = t >> 5;
  float acc[2][4] = {};
  for (int d = 0; d < 64; ++d) {
    float a0 = hr[ty][d], a1 = hr[ty + 8][d];
    float q0 = hp[tx][d], q1 = hp[tx + 32][d], q2 = hp[tx + 64][d], q3 = hp[tx + 96][d];
    acc[0][0] = fmaf(a0, q0, acc[0][0]); acc[0][1] = fmaf(a0, q1, acc[0][1]);
    acc[0][2] = fmaf(a0, q2, acc[0][2]); acc[0][3] = fmaf(a0, q3, acc[0][3]);
    acc[1][0] = fmaf(a1, q0, acc[1][0]); acc[1][1] = fmaf(a1, q1, acc[1][1]);
    acc[1][2] = fmaf(a1, q2, acc[1][2]); acc[1][3] = fmaf(a1, q3, acc[1][3]);
  }
#pragma unroll
  for (int ii = 0; ii < 2; ++ii) {
    int r = r0 + ty + 8 * ii;
    float* mrow = Mhat + ((size_t)(b * 128 + r)) * 128;
    mrow[tx] = acc[ii][0]; mrow[tx + 32] = acc[ii][1];
    mrow[tx + 64] = acc[ii][2]; mrow[tx + 96] = acc[ii][3];
    float mx = redmax32(fmaxf(fmaxf(acc[ii][0], acc[ii][1]), fmaxf(acc[ii][2], acc[ii][3])));
    float e0 = __expf(acc[ii][0] - mx), e1 = __expf(acc[ii][1] - mx);
    float e2 = __expf(acc[ii][2] - mx), e3 = __expf(acc[ii][3] - mx);
    float inv = 1.0f / redsum32(e0 + e1 + e2 + e3);
    float* orow = M0out + ((size_t)(b * 128 + r)) * 128;
    orow[tx] = e0 * inv; orow[tx + 32] = e1 * inv;
    orow[tx + 64] = e2 * inv; orow[tx + 96] = e3 * inv;
    int rl = ty + 8 * ii;
    sm[rl][tx] = e0 * inv; sm[rl][tx + 32] = e1 * inv;
    sm[rl][tx + 64] = e2 * inv; sm[rl][tx + 96] = e3 * inv;
  }
  __syncthreads();
  rfp_partial(sm, rfb, rfp + (size_t)b * 4096, t);
}

// ====== node2u: o = relu(rf@Ws2 + agg + g2b); u = o@W1 (+b1);
//        re-zeroes agg; P-blocks re-zero their rfp slice for next-iter atomics ======
__global__ __launch_bounds__(256) void node2u_gemm(
    const float* __restrict__ rfR, float* __restrict__ aggR, float* __restrict__ uR,
    const float* __restrict__ rfP, float* __restrict__ aggP, float* __restrict__ uP,
    const float* __restrict__ Ws2, const float* __restrict__ g2b,
    const float* __restrict__ W1, const float* __restrict__ b1,
    float* __restrict__ rfp_clear) {
  __shared__ float sRF[32][68];
  __shared__ float sW2[32][68];
  __shared__ float sW1[64][68];
  __shared__ float sO[64][68];
  bool isP = blockIdx.x >= 128;
  const float* rf = isP ? rfP : rfR;
  float* agg = isP ? aggP : aggR;
  float* u = isP ? uP : uR;
  int n0 = (blockIdx.x & 127) * 64;
  int t = threadIdx.x;
#pragma unroll
  for (int idx = 0; idx < 4; ++idx) {
    int q = t * 4 + idx * 1024;
    *reinterpret_cast<float4*>(&sW1[q >> 6][q & 63]) = *reinterpret_cast<const float4*>(W1 + q);
  }
#pragma unroll
  for (int idx = 0; idx < 2; ++idx) {
    int q = t * 4 + idx * 1024;
    // Ws2 is [32][64] row-major: row = q>>6, col = q&63   (bugfix: was q>>5/q&31)
    *reinterpret_cast<float4*>(&sW2[q >> 6][q & 63]) = *reinterpret_cast<const float4*>(Ws2 + q);
    int r = q >> 5, kk = q & 31;
    float4 v = *reinterpret_cast<const float4*>(rf + (size_t)(n0 + r) * 32 + kk);
    sRF[kk][r] = v.x; sRF[kk + 1][r] = v.y; sRF[kk + 2][r] = v.z; sRF[kk + 3][r] = v.w;
  }
  __syncthreads();
  if (isP) {  // this block's rfp slice is fully staged; re-arm for upd_soft atomics
    float4 z4 = make_float4(0.f, 0.f, 0.f, 0.f);
    float4* rz = reinterpret_cast<float4*>(rfp_clear + (size_t)n0 * 32);
    rz[t * 2] = z4; rz[t * 2 + 1] = z4;
  }
  int tn = (t & 15) * 4, tj = (t >> 4) * 4;
  float acc[4][4] = {};
#pragma unroll 8
  for (int k = 0; k < 32; ++k) {
    float4 a = *reinterpret_cast<const float4*>(&sRF[k][tn]);
    float4 b = *reinterpret_cast<const float4*>(&sW2[k][tj]);
    acc[0][0] = fmaf(a.x, b.x, acc[0][0]); acc[0][1] = fmaf(a.x, b.y, acc[0][1]);
    acc[0][2] = fmaf(a.x, b.z, acc[0][2]); acc[0][3] = fmaf(a.x, b.w, acc[0][3]);
    acc[1][0] = fmaf(a.y, b.x, acc[1][0]); acc[1][1] = fmaf(a.y, b.y, acc[1][1]);
    acc[1][2] = fmaf(a.y, b.z, acc[1][2]); acc[1][3] = fmaf(a.y, b.w, acc[1][3]);
    acc[2][0] = fmaf(a.z, b.x, acc[2][0]); acc[2][1] = fmaf(a.z, b.y, acc[2][1]);
    acc[2][2] = fmaf(a.z, b.z, acc[2][2]); acc[2][3] = fmaf(a.z, b.w, acc[2][3]);
    acc[3][0] = fmaf(a.w, b.x, acc[3][0]); acc[3][1] = fmaf(a.w, b.y, acc[3][1]);
    acc[3][2] = fmaf(a.w, b.z, acc[3][2]); acc[3][3] = fmaf(a.w, b.w, acc[3][3]);
  }
  float4 bg = *reinterpret_cast<const float4*>(g2b + tj);
  float4 z4 = make_float4(0.f, 0.f, 0.f, 0.f);
#pragma unroll
  for (int i = 0; i < 4; ++i) {
    int n = n0 + tn + i;
    float4 g = *reinterpret_cast<const float4*>(&agg[(size_t)n * 64 + tj]);
    *reinterpret_cast<float4*>(&agg[(size_t)n * 64 + tj]) = z4;  // re-arm for next iter
    sO[tj + 0][tn + i] = fmaxf(acc[i][0] + g.x + bg.x, 0.f);
    sO[tj + 1][tn + i] = fmaxf(acc[i][1] + g.y + bg.y, 0.f);
    sO[tj + 2][tn + i] = fmaxf(acc[i][2] + g.z + bg.z, 0.f);
    sO[tj + 3][tn + i] = fmaxf(acc[i][3] + g.w + bg.w, 0.f);
  }
  __syncthreads();
  float acc2[4][4] = {};
#pragma unroll 8
  for (int k = 0; k < 64; ++k) {
    float4 a = *reinterpret_cast<const float4*>(&sO[k][tn]);
    float4 b = *reinterpret_cast<const float4*>(&sW1[k][tj]);
    acc2[0][0] = fmaf(a.x, b.x, acc2[0][0]); acc2[0][1] = fmaf(a.x, b.y, acc2[0][1]);
    acc2[0][2] = fmaf(a.x, b.z, acc2[0][2]); acc2[0][3] = fmaf(a.x, b.w, acc2[0][3]);
    acc2[1][0] = fmaf(a.y, b.x, acc2[1][0]); acc2[1][1] = fmaf(a.y, b.y, acc2[1][1]);
    acc2[1][2] = fmaf(a.y, b.z, acc2[1][2]); acc2[1][3] = fmaf(a.y, b.w, acc2[1][3]);
    acc2[2][0] = fmaf(a.z, b.x, acc2[2][0]); acc2[2][1] = fmaf(a.z, b.y, acc2[2][1]);
    acc2[2][2] = fmaf(a.z, b.z, acc2[2][2]); acc2[2][3] = fmaf(a.z, b.w, acc2[2][3]);
    acc2[3][0] = fmaf(a.w, b.x, acc2[3][0]); acc2[3][1] = fmaf(a.w, b.y, acc2[3][1]);
    acc2[3][2] = fmaf(a.w, b.z, acc2[3][2]); acc2[3][3] = fmaf(a.w, b.w, acc2[3][3]);
  }
  float4 b1v = make_float4(0.f, 0.f, 0.f, 0.f);
  if (!isP) b1v = *reinterpret_cast<const float4*>(b1 + tj);
#pragma unroll
  for (int i = 0; i < 4; ++i) {
    int n = n0 + tn + i;
    float4 o;
    o.x = acc2[i][0] + b1v.x; o.y = acc2[i][1] + b1v.y;
    o.z = acc2[i][2] + b1v.z; o.w = acc2[i][3] + b1v.w;
    *reinterpret_cast<float4*>(&u[(size_t)n * 64 + tj]) = o;
  }
}

// ====== upd_soft: Mhat += pairwise MLP; fused row softmax (in-reg);
//        non-last: RNG next rfr tile + rfp_{next} partial; last: write out ======
__global__ __launch_bounds__(256) void upd_soft(
    const float* __restrict__ uR, const float* __restrict__ uP,
    const float* __restrict__ W2, const float* __restrict__ b2p,
    float* __restrict__ Mhat, float* __restrict__ outLast, int last,
    float* __restrict__ rfr, float* __restrict__ rfp,
    unsigned fk0, unsigned fk1) {
  __shared__ float sur[16][66];
  __shared__ float sup[128][66];
  __shared__ float sw2[64];
  __shared__ float sm[16][128];
  __shared__ float rfb[16][32];
  int gid = blockIdx.x, t = threadIdx.x;
  int b = gid >> 3, r0 = (gid & 7) * 16;
  if (!last) gen_rfr_tile(rfr, rfb, b, r0, t, fk0, fk1);
  const float* urG = uR + ((size_t)(b * 128 + r0)) * 64;
  {
    int q = t * 4; int r = q >> 6, d = q & 63;
    float4 v = *reinterpret_cast<const float4*>(urG + q);
    sur[r][d] = v.x; sur[r][d + 1] = v.y; sur[r][d + 2] = v.z; sur[r][d + 3] = v.w;
  }
  const float* upG = uP + (size_t)b * 128 * 64;
#pragma unroll
  for (int rep = 0; rep < 8; ++rep) {
    int q = (rep * 256 + t) * 4; int p = q >> 6, d = q & 63;
    float4 v = *reinterpret_cast<const float4*>(upG + q);
    sup[p][d] = v.x; sup[p][d + 1] = v.y; sup[p][d + 2] = v.z; sup[p][d + 3] = v.w;
  }
  if (t < 64) sw2[t] = W2[t];
  __syncthreads();
  int tx = t & 31, ty = t >> 5;
  float acc[2][4] = {};
  for (int j = 0; j < 64; ++j) {
    float w2v = sw2[j];
    float a0 = sur[ty][j], a1 = sur[ty + 8][j];
    float q0 = sup[tx][j], q1 = sup[tx + 32][j], q2 = sup[tx + 64][j], q3 = sup[tx + 96][j];
    acc[0][0] = fmaf(fmaxf(a0 - q0, 0.f), w2v, acc[0][0]);
    acc[0][1] = fmaf(fmaxf(a0 - q1, 0.f), w2v, acc[0][1]);
    acc[0][2] = fmaf(fmaxf(a0 - q2, 0.f), w2v, acc[0][2]);
    acc[0][3] = fmaf(fmaxf(a0 - q3, 0.f), w2v, acc[0][3]);
    acc[1][0] = fmaf(fmaxf(a1 - q0, 0.f), w2v, acc[1][0]);
    acc[1][1] = fmaf(fmaxf(a1 - q1, 0.f), w2v, acc[1][1]);
    acc[1][2] = fmaf(fmaxf(a1 - q2, 0.f), w2v, acc[1][2]);
    acc[1][3] = fmaf(fmaxf(a1 - q3, 0.f), w2v, acc[1][3]);
  }
  float b2v = b2p[0];
#pragma unroll
  for (int ii = 0; ii < 2; ++ii) {
    int r = r0 + ty + 8 * ii;
    float* mrow = Mhat + ((size_t)(b * 128 + r)) * 128;
    float m0 = mrow[tx] + acc[ii][0] + b2v;
    float m1 = mrow[tx + 32] + acc[ii][1] + b2v;
    float m2 = mrow[tx + 64] + acc[ii][2] + b2v;
    float m3 = mrow[tx + 96] + acc[ii][3] + b2v;
    if (!last) {
      mrow[tx] = m0; mrow[tx + 32] = m1; mrow[tx + 64] = m2; mrow[tx + 96] = m3;
    }
    float mx = redmax32(fmaxf(fmaxf(m0, m1), fmaxf(m2, m3)));
    float e0 = __expf(m0 - mx), e1 = __expf(m1 - mx);
    float e2 = __expf(m2 - mx), e3 = __expf(m3 - mx);
    float inv = 1.0f / redsum32(e0 + e1 + e2 + e3);
    if (last) {
      float* orow = outLast + ((size_t)(b * 128 + r)) * 128;
      orow[tx] = e0 * inv; orow[tx + 32] = e1 * inv;
      orow[tx + 64] = e2 * inv; orow[tx + 96] = e3 * inv;
    } else {
      int rl = ty + 8 * ii;
      sm[rl][tx] = e0 * inv; sm[rl][tx + 32] = e1 * inv;
      sm[rl][tx + 64] = e2 * inv; sm[rl][tx + 96] = e3 * inv;
    }
  }
  if (!last) {
    __syncthreads();
    rfp_partial(sm, rfb, rfp + (size_t)b * 4096, t);
  }
}

extern "C" void kernel_launch(void* const* d_in, const int* in_sizes, int n_in,
                              void* d_out, int out_size, void* d_ws, size_t ws_size,
                              hipStream_t stream) {
  (void)in_sizes; (void)n_in; (void)out_size; (void)ws_size;
  const float* x_r  = (const float*)d_in[0];
  const int*   ei_r = (const int*)d_in[1];
  const float* ef_r = (const float*)d_in[2];
  const float* x_p  = (const float*)d_in[3];
  const int*   ei_p = (const int*)d_in[4];
  const float* ef_p = (const float*)d_in[5];
  const float* g1_Ws = (const float*)d_in[8];
  const float* g1_Wm = (const float*)d_in[9];
  const float* g1_We = (const float*)d_in[10];
  const float* g1_b  = (const float*)d_in[11];
  const float* g2_Ws = (const float*)d_in[12];
  const float* g2_Wm = (const float*)d_in[13];
  const float* g2_We = (const float*)d_in[14];
  const float* g2_b  = (const float*)d_in[15];
  const float* W1 = (const float*)d_in[16];
  const float* b1 = (const float*)d_in[17];
  const float* W2 = (const float*)d_in[18];
  const float* b2 = (const float*)d_in[19];
  float* out = (float*)d_out;

  float* ws = (float*)d_ws;
  float* h_r   = ws;                 // 524288
  float* h_p   = h_r + 524288;       // 524288
  float* Mhat  = h_p + 524288;       // 1048576
  float* rfr   = Mhat + 1048576;     // 262144
  float* rfp   = rfr + 262144;       // 262144
  float* u_r   = rfp + 262144;       // 524288
  float* u_p   = u_r + 524288;       // 524288
  float* agg_r = u_p + 524288;       // 524288
  float* agg_p = agg_r + 524288;     // 524288 (contiguous for zeroing)
  float* xw_r  = agg_p + 524288;     // 524288 (per-node x@Wm / rf@Wm2)
  float* xw_p  = xw_r + 524288;      // 524288
  int* ib      = (int*)(xw_p + 524288);
  int* off_r  = ib;                  // 8192 (zeroed)
  int* off_p  = off_r + 8192;        // 8192
  int* perm_r = off_p + 8192;        // 65536
  int* perm_p = perm_r + 65536;      // 65536
  int* srcs_r = perm_p + 65536;      // 65536
  int* srcs_p = srcs_r + 65536;      // 65536
  int* dsts_r = srcs_p + 65536;      // 65536
  int* dsts_p = dsts_r + 65536;      // 65536

  unsigned fk0[3], fk1[3];
  for (int it = 0; it < 3; ++it) {
    unsigned a = 0u, c = (unsigned)it;
    tf2x32(0u, 42u, a, c);
    fk0[it] = a; fk1[it] = c;
  }

  // ---- CSR build + agg/rfp zeroing ----
  hipMemsetAsync(off_r, 0, 2 * 8192 * sizeof(int), stream);
  hist_kern<<<512, 256, 0, stream>>>(ei_r, ei_p, off_r, off_p, agg_r, rfp);
  scan_kern<<<2, 256, 0, stream>>>(off_r, off_p);
  scatter_kern<<<512, 256, 0, stream>>>(ei_r, ei_p, off_r, off_p,
                                        perm_r, perm_p, srcs_r, srcs_p,
                                        dsts_r, dsts_p);

  // ---- gnn1: xw = x@Wm1 per node, then K=16 edge pass + gather-add ----
  xw_gemm<64><<<256, 256, 0, stream>>>(x_r, x_p, xw_r, xw_p, g1_Wm);
  msg_edge<<<2048, 256, 0, stream>>>(xw_r, ef_r, srcs_r, perm_r, dsts_r, agg_r,
                                     xw_p, ef_p, srcs_p, perm_p, dsts_p, agg_p,
                                     g1_We);
  node1_gemm<<<256, 256, 0, stream>>>(x_r, agg_r, h_r, x_p, agg_p, h_p, g1_Ws, g1_b);
  mhat_soft<<<512, 256, 0, stream>>>(h_r, h_p, Mhat, out, rfr, rfp, fk0[0], fk1[0]);

  for (int it = 0; it < 3; ++it) {
    xw_gemm<32><<<256, 256, 0, stream>>>(rfr, rfp, xw_r, xw_p, g2_Wm);
    msg_edge<<<2048, 256, 0, stream>>>(xw_r, ef_r, srcs_r, perm_r, dsts_r, agg_r,
                                       xw_p, ef_p, srcs_p, perm_p, dsts_p, agg_p,
                                       g2_We);
    node2u_gemm<<<256, 256, 0, stream>>>(rfr, agg_r, u_r, rfp, agg_p, u_p,
                                         g2_Ws, g2_b, W1, b1, rfp);
    int last = (it == 2);
    upd_soft<<<512, 256, 0, stream>>>(u_r, u_p, W2, b2, Mhat,
                                      out + 1048576, last,
                                      rfr, rfp,
                                      fk0[it < 2 ? it + 1 : 0], fk1[it < 2 ? it + 1 : 0]);
  }
}